// Round 9
// baseline (93.506 us; speedup 1.0000x reference)
//
#include <hip/hip_runtime.h>

#define BN 2
#define T_DIM 2048
#define D_DIM 1024
#define H_N 16
#define DH_N 64
#define WIN 256
#define NROWS (BN * T_DIM)   // 4096
#define KDIM 1024            // inner dim for all GEMMs

typedef __attribute__((ext_vector_type(8))) short bf16x8;
typedef __attribute__((ext_vector_type(4))) float f32x4;
typedef __attribute__((ext_vector_type(8))) unsigned short ushort8;
typedef __attribute__((ext_vector_type(4))) unsigned short u16x4;

static __device__ __forceinline__ unsigned short f2bf(float f) {
  unsigned int u = __float_as_uint(f);
  unsigned int r = (u + 0x7FFFu + ((u >> 16) & 1u)) >> 16;  // RNE
  return (unsigned short)r;
}

static __device__ __forceinline__ void gl_lds16(const void* g, void* l) {
  __builtin_amdgcn_global_load_lds(
      (const __attribute__((address_space(1))) unsigned int*)g,
      (__attribute__((address_space(3))) unsigned int*)l, 16, 0, 0);
}

#define MFMA16(a, b, c) __builtin_amdgcn_mfma_f32_16x16x32_bf16(a, b, c, 0, 0, 0)

// ---------------------------------------------------------------------------
// Merged conversions (one launch): x f32->bf16 (blocks 0..2047),
// w_qkv^T (2048..2815), w_out^T (2816..3071).
// ---------------------------------------------------------------------------
static __device__ __forceinline__ void transpose_tile(
    const float* __restrict__ src, unsigned short* __restrict__ dst, int R,
    int C, int bx, int by, float* tile /* [64][65] */) {
  const int t = threadIdx.x;
  const int bc = bx * 64, br = by * 64;
#pragma unroll
  for (int i = 0; i < 16; ++i) {
    int idx = i * 256 + t;
    int r = idx >> 6, c = idx & 63;
    tile[r * 65 + c] = src[(size_t)(br + r) * C + bc + c];
  }
  __syncthreads();
#pragma unroll
  for (int i = 0; i < 16; ++i) {
    int idx = i * 256 + t;
    int r = idx >> 6, c = idx & 63;
    dst[(size_t)(bc + r) * R + br + c] = f2bf(tile[c * 65 + r]);
  }
}

__global__ __launch_bounds__(256) void convert_all(
    const float* __restrict__ x, const float* __restrict__ w_qkv,
    const float* __restrict__ w_out, unsigned short* __restrict__ xbf,
    unsigned short* __restrict__ wqkvt, unsigned short* __restrict__ woutt) {
  __shared__ float tile[64 * 65];
  const int id = blockIdx.x;
  if (id < 2048) {
    int i = (id * 256 + threadIdx.x) * 8;
    float4 a = *(const float4*)(x + i);
    float4 b = *(const float4*)(x + i + 4);
    ushort8 o;
    o[0] = f2bf(a.x); o[1] = f2bf(a.y); o[2] = f2bf(a.z); o[3] = f2bf(a.w);
    o[4] = f2bf(b.x); o[5] = f2bf(b.y); o[6] = f2bf(b.z); o[7] = f2bf(b.w);
    *(ushort8*)(xbf + i) = o;
  } else if (id < 2816) {
    int j = id - 2048;  // 48 x 16
    transpose_tile(w_qkv, wqkvt, D_DIM, 3 * D_DIM, j % 48, j / 48, tile);
  } else {
    int j = id - 2816;  // 16 x 16
    transpose_tile(w_out, woutt, D_DIM, D_DIM, j % 16, j / 16, tile);
  }
}

// ---------------------------------------------------------------------------
// qkv GEMM: 128x128 tile, BK=64, grid 32x24 = 768 blocks, 256 thr (4 waves
// 2x2, per-wave 64x64). Double-buffered 64KB LDS -> 2 blocks/CU (implicit
// wave overlap). ONE barrier per K-tile: [vmcnt(0, covered); barrier;
// stage(next, other buf); 32 MFMA]. Zero-conflict XOR swizzle (row&7 on
// 128B rows), pre-swizzled global source. T1 XCD swizzle, T5 setprio.
// Epilogue: q,k bf16 [B,H,T,64] (q*0.125), v^T bf16 [B,H,64,T].
// ---------------------------------------------------------------------------
__global__ __launch_bounds__(256) void gemm_qkv_db(
    const unsigned short* __restrict__ A, const unsigned short* __restrict__ Bt,
    const float* __restrict__ bias, unsigned short* __restrict__ qo,
    unsigned short* __restrict__ ko, unsigned short* __restrict__ vto) {
  __shared__ unsigned short As[2][128 * 64];  // 2 x 16 KB
  __shared__ unsigned short Bs[2][128 * 64];  // 2 x 16 KB

  const int tid = threadIdx.x;
  const int w = tid >> 6, l = tid & 63;
  const int wr = w >> 1, wc = w & 1;
  const int l15 = l & 15, kslc = l >> 4;

  // T1: bijective XCD swizzle (nwg = 768, 96 per XCD)
  const int id = blockIdx.x;
  const int wg = (id & 7) * 96 + (id >> 3);
  const int bx = wg % 24, by = wg / 24;
  const int r0 = by * 128, c0 = bx * 128;

  const unsigned short* Ag = A + (size_t)r0 * KDIM;
  const unsigned short* Bg = Bt + (size_t)c0 * KDIM;

  f32x4 acc[4][4];
#pragma unroll
  for (int i = 0; i < 4; ++i)
#pragma unroll
    for (int j = 0; j < 4; ++j) acc[i][j] = (f32x4){0.f, 0.f, 0.f, 0.f};

  // staging: 4 chunks x 32 rows per operand; thread -> row tid>>3, slot tid&7
  // dest linear (chunk*4096 + tid*16); source slot pre-swizzled by row&7.
  const int grow = tid >> 3;
  const int gcol = (tid & 7) ^ (grow & 7);

#define STG(T, BUF)                                                            \
  do {                                                                         \
    const size_t kk0 = (size_t)(T) * 64;                                       \
    _Pragma("unroll") for (int ch = 0; ch < 4; ++ch) {                         \
      gl_lds16(Ag + (size_t)(ch * 32 + grow) * KDIM + kk0 + gcol * 8,          \
               (char*)&As[BUF][0] + ch * 4096 + w * 1024);                     \
      gl_lds16(Bg + (size_t)(ch * 32 + grow) * KDIM + kk0 + gcol * 8,          \
               (char*)&Bs[BUF][0] + ch * 4096 + w * 1024);                     \
    }                                                                          \
  } while (0)

#define LDA(CB, mi, ks)                                                        \
  (*(const bf16x8*)((const char*)&As[CB][0] +                                  \
                    (wr * 64 + (mi)*16 + l15) * 128 +                          \
                    ((((ks)*4 + kslc) ^ (l15 & 7)) << 4)))
#define LDB(CB, ni, ks)                                                        \
  (*(const bf16x8*)((const char*)&Bs[CB][0] +                                  \
                    (wc * 64 + (ni)*16 + l15) * 128 +                          \
                    ((((ks)*4 + kslc) ^ (l15 & 7)) << 4)))

#define HALF(CB, ks)                                                           \
  do {                                                                         \
    bf16x8 a0 = LDA(CB, 0, ks), a1 = LDA(CB, 1, ks), a2 = LDA(CB, 2, ks),      \
           a3 = LDA(CB, 3, ks);                                                \
    bf16x8 b0 = LDB(CB, 0, ks), b1 = LDB(CB, 1, ks), b2 = LDB(CB, 2, ks),      \
           b3 = LDB(CB, 3, ks);                                                \
    __builtin_amdgcn_s_setprio(1);                                             \
    acc[0][0] = MFMA16(a0, b0, acc[0][0]);                                     \
    acc[0][1] = MFMA16(a0, b1, acc[0][1]);                                     \
    acc[0][2] = MFMA16(a0, b2, acc[0][2]);                                     \
    acc[0][3] = MFMA16(a0, b3, acc[0][3]);                                     \
    acc[1][0] = MFMA16(a1, b0, acc[1][0]);                                     \
    acc[1][1] = MFMA16(a1, b1, acc[1][1]);                                     \
    acc[1][2] = MFMA16(a1, b2, acc[1][2]);                                     \
    acc[1][3] = MFMA16(a1, b3, acc[1][3]);                                     \
    acc[2][0] = MFMA16(a2, b0, acc[2][0]);                                     \
    acc[2][1] = MFMA16(a2, b1, acc[2][1]);                                     \
    acc[2][2] = MFMA16(a2, b2, acc[2][2]);                                     \
    acc[2][3] = MFMA16(a2, b3, acc[2][3]);                                     \
    acc[3][0] = MFMA16(a3, b0, acc[3][0]);                                     \
    acc[3][1] = MFMA16(a3, b1, acc[3][1]);                                     \
    acc[3][2] = MFMA16(a3, b2, acc[3][2]);                                     \
    acc[3][3] = MFMA16(a3, b3, acc[3][3]);                                     \
    __builtin_amdgcn_s_setprio(0);                                             \
  } while (0)

  STG(0, 0);
#pragma unroll 2
  for (int t = 0; t < 15; ++t) {
    const int cb = t & 1;
    // tile-t loads were issued one full compute-iteration ago -> covered
    asm volatile("s_waitcnt vmcnt(0)" ::: "memory");
    __builtin_amdgcn_s_barrier();  // all waves: tile-t landed AND buf cb^1 free
    STG(t + 1, cb ^ 1);
    HALF(cb, 0);
    HALF(cb, 1);
  }
  asm volatile("s_waitcnt vmcnt(0)" ::: "memory");
  __builtin_amdgcn_s_barrier();
  HALF(1, 0);
  HALF(1, 1);
#undef STG
#undef LDA
#undef LDB
#undef HALF

  // epilogue: head decode per 16-col fragment (c0 is 128-aligned, 64 | c0)
#pragma unroll
  for (int ni = 0; ni < 4; ++ni) {
    const int col0 = c0 + wc * 64 + ni * 16;
    const int which = col0 >> 10;  // 0=q,1=k,2=v
    const int h = (col0 >> 6) & 15;
    const int dh = (col0 & 63) + l15;
    const float bv = bias[col0 + l15];
#pragma unroll
    for (int mi = 0; mi < 4; ++mi) {
      int row = r0 + wr * 64 + mi * 16 + (l >> 4) * 4;  // multiple of 4
      int b_ = row >> 11, t0 = row & 2047;
      if (which == 2) {
        u16x4 pk;
#pragma unroll
        for (int j = 0; j < 4; ++j) pk[j] = f2bf(acc[mi][ni][j] + bv);
        *(u16x4*)(vto + ((size_t)(b_ * H_N + h) * DH_N + dh) * T_DIM + t0) = pk;
      } else {
        float mul = (which == 0) ? 0.125f : 1.0f;
        unsigned short* dst = (which == 0) ? qo : ko;
#pragma unroll
        for (int j = 0; j < 4; ++j)
          dst[((size_t)(b_ * H_N + h) * T_DIM + t0 + j) * DH_N + dh] =
              f2bf((acc[mi][ni][j] + bv) * mul);
      }
    }
  }
}

// ---------------------------------------------------------------------------
// out-proj GEMM (unchanged, performing ~950 TF-class): 128x128, quad-buffer,
// lead-2, one barrier/iter, counted vmcnt(8).
// ---------------------------------------------------------------------------
__global__ __launch_bounds__(256) void gemm_out_p4(
    const unsigned short* __restrict__ A, const unsigned short* __restrict__ Bt,
    const float* __restrict__ bias, float* __restrict__ fo) {
  __shared__ unsigned short As[4][4096];
  __shared__ unsigned short Bs[4][4096];

  const int tid = threadIdx.x;
  const int w = tid >> 6, l = tid & 63;
  const int wr = w >> 1, wc = w & 1;
  const int l15 = l & 15, kslc = l >> 4;

  const int id = blockIdx.x;
  const int wg = (id & 7) * 32 + (id >> 3);
  const int bx = wg & 7, by = wg >> 3;
  const int r0 = by * 128, c0 = bx * 128;

  const unsigned short* Ag = A + (size_t)r0 * KDIM;
  const unsigned short* Bg = Bt + (size_t)c0 * KDIM;

  f32x4 acc[4][4];
#pragma unroll
  for (int i = 0; i < 4; ++i)
#pragma unroll
    for (int j = 0; j < 4; ++j) acc[i][j] = (f32x4){0.f, 0.f, 0.f, 0.f};

  const int srow = l >> 2;
  const int srcslot = (l & 3) ^ ((l >> 3) & 3);

#define STAGE_O(T, BUF)                                                        \
  do {                                                                         \
    const size_t kk0 = (size_t)(T) * 32;                                       \
    gl_lds16(Ag + (size_t)(w * 16 + srow) * KDIM + kk0 + srcslot * 8,          \
             (char*)&As[BUF][0] + w * 1024);                                   \
    gl_lds16(Ag + (size_t)(64 + w * 16 + srow) * KDIM + kk0 + srcslot * 8,     \
             (char*)&As[BUF][0] + (4 + w) * 1024);                             \
    gl_lds16(Bg + (size_t)(w * 16 + srow) * KDIM + kk0 + srcslot * 8,          \
             (char*)&Bs[BUF][0] + w * 1024);                                   \
    gl_lds16(Bg + (size_t)(64 + w * 16 + srow) * KDIM + kk0 + srcslot * 8,     \
             (char*)&Bs[BUF][0] + (4 + w) * 1024);                             \
  } while (0)

#define OCOMPUTE(CB)                                                           \
  do {                                                                         \
    bf16x8 af[4], bfr[4];                                                      \
    _Pragma("unroll") for (int mi = 0; mi < 4; ++mi) {                         \
      int row = wr * 64 + mi * 16 + l15;                                       \
      af[mi] = *(const bf16x8*)((const char*)&As[CB][0] + row * 64 +           \
                                ((kslc ^ ((row >> 1) & 3)) << 4));             \
    }                                                                          \
    _Pragma("unroll") for (int ni = 0; ni < 4; ++ni) {                         \
      int row = wc * 64 + ni * 16 + l15;                                       \
      bfr[ni] = *(const bf16x8*)((const char*)&Bs[CB][0] + row * 64 +          \
                                 ((kslc ^ ((row >> 1) & 3)) << 4));            \
    }                                                                          \
    __builtin_amdgcn_s_setprio(1);                                             \
    _Pragma("unroll") for (int mi = 0; mi < 4; ++mi)                           \
        _Pragma("unroll") for (int ni = 0; ni < 4; ++ni) acc[mi][ni] =         \
            MFMA16(af[mi], bfr[ni], acc[mi][ni]);                              \
    __builtin_amdgcn_s_setprio(0);                                             \
  } while (0)

  STAGE_O(0, 0);
  STAGE_O(1, 1);

  for (int t = 0; t < 30; ++t) {
    STAGE_O(t + 2, (t + 2) & 3);
    asm volatile("s_waitcnt vmcnt(8)" ::: "memory");
    __builtin_amdgcn_s_barrier();
    OCOMPUTE(t & 3);
  }
  asm volatile("s_waitcnt vmcnt(4)" ::: "memory");
  __builtin_amdgcn_s_barrier();
  OCOMPUTE(2);
  asm volatile("s_waitcnt vmcnt(0)" ::: "memory");
  __builtin_amdgcn_s_barrier();
  OCOMPUTE(3);
#undef STAGE_O
#undef OCOMPUTE

#pragma unroll
  for (int mi = 0; mi < 4; ++mi) {
#pragma unroll
    for (int ni = 0; ni < 4; ++ni) {
      int row = r0 + wr * 64 + mi * 16 + (l >> 4) * 4;
      int col = c0 + wc * 64 + ni * 16 + l15;
      float bv = bias[col];
#pragma unroll
      for (int j = 0; j < 4; ++j)
        fo[(size_t)(row + j) * D_DIM + col] = acc[mi][ni][j] + bv;
    }
  }
}

// ---------------------------------------------------------------------------
// MFMA windowed flash attention, double-buffered K/V with single barrier
// per tile and covered vmcnt (stage issued one full compute earlier).
// ---------------------------------------------------------------------------
__global__ __launch_bounds__(256) void attn_mfma(
    const unsigned short* __restrict__ qbf,
    const unsigned short* __restrict__ kbf,
    const unsigned short* __restrict__ vtbf,
    unsigned short* __restrict__ ctx) {
  __shared__ unsigned short Ks[2][64 * 64];
  __shared__ unsigned short Vs[2][64 * 64];
  const int tid = threadIdx.x;
  const int w = tid >> 6, l = tid & 63;
  const int g = l >> 4, ln = l & 15;
  const int qt = blockIdx.x & 31;
  const int bh = blockIdx.x >> 5;
  const int q0 = qt * 64;
  const int q_abs = q0 + w * 16 + ln;

  const unsigned short* kp = kbf + (size_t)bh * T_DIM * DH_N;
  const unsigned short* vtp = vtbf + (size_t)bh * DH_N * T_DIM;

  bf16x8 qf0, qf1;
  {
    const unsigned short* qp = qbf + ((size_t)bh * T_DIM + q_abs) * DH_N;
    qf0 = *(const bf16x8*)(qp + g * 8);
    qf1 = *(const bf16x8*)(qp + 32 + g * 8);
  }

  // staging constants (4 gl_lds16/thread/tile)
  const int srow = tid >> 2, sc16a = (tid & 3) ^ (srow & 7);
  const int srow2 = srow + 64 >> 0;  // second half rows 64..127 of chunk idx
  // kap permutation for K rows (makes S^T layout == PV B-frag layout)
#define KAP(row) \
  (32 * (((row) >> 4) & 1) + 8 * (((row)&15) >> 2) + 4 * ((row) >> 5) + ((row)&3))

#define STAGEKV(KT, BUF)                                                       \
  do {                                                                         \
    _Pragma("unroll") for (int i_ = 0; i_ < 2; ++i_) {                         \
      int chunk = i_ * 256 + tid;                                              \
      int row = chunk >> 3, c16 = chunk & 7;                                   \
      int sc16 = c16 ^ (row & 7);                                              \
      int kap = KAP(row);                                                      \
      gl_lds16(kp + (size_t)((KT) + kap) * DH_N + sc16 * 8,                    \
               (char*)&Ks[BUF][0] + chunk * 16);                               \
      gl_lds16(vtp + (size_t)row * T_DIM + (KT) + sc16 * 8,                    \
               (char*)&Vs[BUF][0] + chunk * 16);                               \
    }                                                                          \
  } while (0)

  f32x4 acc_o[4];
#pragma unroll
  for (int nd = 0; nd < 4; ++nd) acc_o[nd] = (f32x4){0.f, 0.f, 0.f, 0.f};
  float m = -1e30f, lsum = 0.f;

  const int kt_lo = (q0 >= WIN) ? (q0 - WIN) : 0;
  const int nt = ((q0 - kt_lo) >> 6) + 1;

  STAGEKV(kt_lo, 0);
  for (int i = 0; i < nt; ++i) {
    const int cb = i & 1;
    const int kt = kt_lo + i * 64;
    asm volatile("s_waitcnt vmcnt(0)" ::: "memory");  // tile-i landed (covered)
    __builtin_amdgcn_s_barrier();   // + all waves done reading buf cb^1
    if (i + 1 < nt) STAGEKV(kt + 64, cb ^ 1);

    // S^T = K · Q^T
    f32x4 sacc[4];
#pragma unroll
    for (int nk = 0; nk < 4; ++nk) sacc[nk] = (f32x4){0.f, 0.f, 0.f, 0.f};
#pragma unroll
    for (int ks = 0; ks < 2; ++ks) {
      bf16x8 qf = ks ? qf1 : qf0;
#pragma unroll
      for (int nk = 0; nk < 4; ++nk) {
        int rrow = nk * 16 + ln;
        int c16 = ks * 4 + g;
        bf16x8 kf = *(const bf16x8*)((const char*)&Ks[cb][0] + rrow * 128 +
                                     ((c16 ^ (rrow & 7)) * 16));
        sacc[nk] = MFMA16(kf, qf, sacc[nk]);
      }
    }

    float p[4][4];
    float tm = -1e30f;
#pragma unroll
    for (int nk = 0; nk < 4; ++nk)
#pragma unroll
      for (int j = 0; j < 4; ++j) {
        int k_abs = kt + 32 * (nk & 1) + 8 * g + 4 * (nk >> 1) + j;
        float s = sacc[nk][j];
        bool ok = (k_abs <= q_abs) && (k_abs + WIN >= q_abs);
        s = ok ? s : -1e30f;
        p[nk][j] = s;
        tm = fmaxf(tm, s);
      }
    tm = fmaxf(tm, __shfl_xor(tm, 16, 64));
    tm = fmaxf(tm, __shfl_xor(tm, 32, 64));
    float mn = fmaxf(m, tm);
    float sc = __expf(m - mn);
    float ps = 0.f;
#pragma unroll
    for (int nk = 0; nk < 4; ++nk)
#pragma unroll
      for (int j = 0; j < 4; ++j) {
        p[nk][j] = __expf(p[nk][j] - mn);
        ps += p[nk][j];
      }
    ps += __shfl_xor(ps, 16, 64);
    ps += __shfl_xor(ps, 32, 64);
    lsum = lsum * sc + ps;
    m = mn;
#pragma unroll
    for (int nd = 0; nd < 4; ++nd) {
      acc_o[nd][0] *= sc; acc_o[nd][1] *= sc;
      acc_o[nd][2] *= sc; acc_o[nd][3] *= sc;
    }

    unsigned int pk[4][2];
#pragma unroll
    for (int nk = 0; nk < 4; ++nk) {
      pk[nk][0] = (unsigned)f2bf(p[nk][0]) | ((unsigned)f2bf(p[nk][1]) << 16);
      pk[nk][1] = (unsigned)f2bf(p[nk][2]) | ((unsigned)f2bf(p[nk][3]) << 16);
    }

#pragma unroll
    for (int ks = 0; ks < 2; ++ks) {
      union { unsigned int d[4]; bf16x8 v; } pf;
      pf.d[0] = pk[ks][0];     pf.d[1] = pk[ks][1];
      pf.d[2] = pk[2 + ks][0]; pf.d[3] = pk[2 + ks][1];
#pragma unroll
      for (int nd = 0; nd < 4; ++nd) {
        int drow = nd * 16 + ln;
        int c16 = ks * 4 + g;
        bf16x8 vf = *(const bf16x8*)((const char*)&Vs[cb][0] + drow * 128 +
                                     ((c16 ^ (drow & 7)) * 16));
        acc_o[nd] = MFMA16(vf, pf.v, acc_o[nd]);
      }
    }
  }
#undef STAGEKV
#undef KAP

  float inv = 1.f / lsum;
  const int b_ = bh >> 4, h = bh & 15;
  unsigned short* op = ctx + ((size_t)b_ * T_DIM + q_abs) * D_DIM + h * DH_N;
#pragma unroll
  for (int nd = 0; nd < 4; ++nd) {
    u16x4 o;
#pragma unroll
    for (int j = 0; j < 4; ++j) o[j] = f2bf(acc_o[nd][j] * inv);
    *(u16x4*)(op + nd * 16 + g * 4) = o;
  }
}

// ---------------------------------------------------------------------------
extern "C" void kernel_launch(void* const* d_in, const int* in_sizes, int n_in,
                              void* d_out, int out_size, void* d_ws,
                              size_t ws_size, hipStream_t stream) {
  const float* x = (const float*)d_in[0];
  const float* w_qkv = (const float*)d_in[1];
  const float* b_qkv = (const float*)d_in[2];
  const float* w_out = (const float*)d_in[3];
  const float* b_out = (const float*)d_in[4];
  float* out = (float*)d_out;

  const size_t per = (size_t)BN * H_N * T_DIM * DH_N;  // 4,194,304
  unsigned short* qbf = (unsigned short*)d_ws;
  unsigned short* kbf = qbf + per;
  unsigned short* vtbf = kbf + per;                    // [B,H,64,T]
  unsigned short* xbf = vtbf + per;                    // [4096][1024]
  unsigned short* wqkvt = xbf + (size_t)NROWS * D_DIM; // [3072][1024]
  unsigned short* woutt = wqkvt + (size_t)3 * D_DIM * D_DIM;  // [1024][1024]
  unsigned short* ctxbf = woutt + (size_t)D_DIM * D_DIM;      // [4096][1024]

  // all conversions in one launch: 2048 + 768 + 256 = 3072 blocks
  convert_all<<<dim3(3072), dim3(256), 0, stream>>>(x, w_qkv, w_out, xbf,
                                                    wqkvt, woutt);

  // qkv: 128x128 tiles -> 32 x 24 = 768 blocks, 256 threads, 2 blocks/CU
  gemm_qkv_db<<<dim3(768), dim3(256), 0, stream>>>(xbf, wqkvt, b_qkv, qbf, kbf,
                                                   vtbf);

  attn_mfma<<<dim3(BN * H_N * (T_DIM / 64)), dim3(256), 0, stream>>>(
      qbf, kbf, vtbf, ctxbf);

  // out-proj: 128x128 tiles -> 32 x 8 = 256 blocks, 256 threads
  gemm_out_p4<<<dim3(256), dim3(256), 0, stream>>>(ctxbf, woutt, b_out, out);
}